// Round 5
// baseline (74.523 us; speedup 1.0000x reference)
//
#include <hip/hip_runtime.h>
#include <math.h>

// Problem constants (match reference)
constexpr int BGR = 1024;   // graphs
constexpr int NN  = 128;    // nodes per graph
constexpr int EG  = 2048;   // edges per graph
constexpr int FIN = 30;
constexpr int H1  = 30;
constexpr int H2  = 50;
constexpr int K1  = 103;    // ceil(0.8*128)
constexpr int K2  = 83;     // ceil(0.8*103)
constexpr int FCW = 100;
constexpr int NT  = 256;
constexpr int EPT = EG/NT;  // 8 edges/thread in registers

// XB: node rows of 32 floats, chunk-rotated swizzle:
//   feature i of row s -> dword s*32 + (((i>>2)+s)&7)*4 + (i&3)
// AGG: aggregated rows, stride 36 floats.
constexpr int SA   = 36;
constexpr int XBSZ = NN*32;        // 16384 B
constexpr int AGSZ = NN*SA;        // 18432 B
// AGG tail scratch (rows >=104 unused: dword 3744..4607)
constexpr int PMAXo = 3744;
constexpr int PSUMo = 3944;
constexpr int POOLo = 4144;
constexpr int ZFCo  = 4244;

__global__ __launch_bounds__(NT, 4) void gnn_fused(
    const float* __restrict__ x, const int* __restrict__ ei,
    const float* __restrict__ W1, const float* __restrict__ b1, const float* __restrict__ p1,
    const float* __restrict__ W2, const float* __restrict__ b2, const float* __restrict__ p2,
    const float* __restrict__ fc1W, const float* __restrict__ fc1b,
    const float* __restrict__ fc2W, const float* __restrict__ fc2b,
    float* __restrict__ out)
{
  const int g = blockIdx.x, tid = threadIdx.x;

  __shared__ float XB[XBSZ];          // x -> W1t -> h1-gated -> W2t
  __shared__ float AGG[AGSZ];         // agg1 -> agg2 (+ tail scratch)
  __shared__ unsigned char eord[EG];
  __shared__ int   cur[NN];
  __shared__ short cstart[NN];
  __shared__ float dsc[NN];           // dinv <-> score (barrier-guarded)
  __shared__ signed char rmap[NN];
  __shared__ unsigned char dperm[NN]; // degree-descending node permutation
  __shared__ int sh_wtot;

  // ---- edge list in registers for the whole kernel ----
  int es[EPT], ed[EPT];
  {
    const int* srcg = ei + (size_t)g*EG;
    const int* dstg = ei + (size_t)BGR*EG + (size_t)g*EG;
    #pragma unroll
    for (int j=0;j<EPT;j++){ int e=tid+j*NT; es[j]=srcg[e]&(NN-1); ed[j]=dstg[e]&(NN-1); }
  }
  // ---- stage x into swizzled XB ----
  for (int l=tid; l<NN*FIN; l+=NT){
    int n=l/FIN, i=l-n*FIN;
    XB[(n<<5) + ((((i>>2)+n)&7)<<2) + (i&3)] = x[(size_t)g*NN*FIN + l];
  }
  if (tid<NN) cur[tid]=0;
  __syncthreads();

  const int nA = tid>>1, hf = tid&1;   // plain pair mapping
  const int lane = tid&63;

  // ================= CSR build 1 (counts -> rank_d + scan -> scatter) ========
  #pragma unroll
  for (int j=0;j<EPT;j++) atomicAdd(&cur[ed[j]],1);
  __syncthreads();
  {
    // degree-descending rank for balance (pair-split, 64 iters)
    int dn = cur[nA];
    int m0 = hf<<6, m1 = m0+64;
    int rk = 0;
    for (int m=m0;m<m1;m++){ int d=cur[m]; rk += (d>dn)||(d==dn && m<nA); }
    rk += __shfl_xor(rk,1,64);
    int mydeg = (tid<NN)? cur[tid] : 0;
    // wave-level inclusive scan of degrees (waves 0,1 carry data)
    int v = mydeg;
    #pragma unroll
    for (int off=1; off<64; off<<=1){ int t=__shfl_up(v,off,64); if (lane>=off) v+=t; }
    if (tid==63) sh_wtot=v;
    __syncthreads();                    // also fences cur reads before overwrite
    int start = v - mydeg + ((tid>=64)? sh_wtot : 0);
    if (tid<NN){ cur[tid]=start; cstart[tid]=(short)start; dsc[tid]=1.0f/sqrtf((float)mydeg+1.0f); }
    if (!hf) dperm[rk]=(unsigned char)nA;
  }
  __syncthreads();
  #pragma unroll
  for (int j=0;j<EPT;j++){ int p=atomicAdd(&cur[ed[j]],1); eord[p]=(unsigned char)es[j]; }
  __syncthreads();

  // ================= gather1: agg1 = A~ * x (balanced, pipelined) ============
  {
    const int gnode = dperm[nA];
    float4 ac0={0,0,0,0},ac1={0,0,0,0},ac2={0,0,0,0},ac3={0,0,0,0};
    const int cq = hf<<2;
    int e0=cstart[gnode], e1=cur[gnode];
    float di=dsc[gnode];
    int s=0; float w=0.f;
    if (e0<e1){ s=eord[e0]; w=di*dsc[s]; }
    for (int k=e0;k<e1;k++){
      int s2=0; float w2=0.f;
      if (k+1<e1){ s2=eord[k+1]; w2=di*dsc[s2]; }
      int base=s<<5, rot=s&7;
      float4 v0=*(const float4*)&XB[base+(((cq  +rot)&7)<<2)];
      float4 v1=*(const float4*)&XB[base+(((cq+1+rot)&7)<<2)];
      float4 v2=*(const float4*)&XB[base+(((cq+2+rot)&7)<<2)];
      float4 v3=*(const float4*)&XB[base+(((cq+3+rot)&7)<<2)];
      ac0.x=fmaf(w,v0.x,ac0.x); ac0.y=fmaf(w,v0.y,ac0.y); ac0.z=fmaf(w,v0.z,ac0.z); ac0.w=fmaf(w,v0.w,ac0.w);
      ac1.x=fmaf(w,v1.x,ac1.x); ac1.y=fmaf(w,v1.y,ac1.y); ac1.z=fmaf(w,v1.z,ac1.z); ac1.w=fmaf(w,v1.w,ac1.w);
      ac2.x=fmaf(w,v2.x,ac2.x); ac2.y=fmaf(w,v2.y,ac2.y); ac2.z=fmaf(w,v2.z,ac2.z); ac2.w=fmaf(w,v2.w,ac2.w);
      ac3.x=fmaf(w,v3.x,ac3.x); ac3.y=fmaf(w,v3.y,ac3.y); ac3.z=fmaf(w,v3.z,ac3.z); ac3.w=fmaf(w,v3.w,ac3.w);
      s=s2; w=w2;
    }
    { // self loop: weight 1/(deg+1)
      float ws=1.0f/((float)(e1-e0)+1.0f);
      int base=gnode<<5, rot=gnode&7;
      float4 v0=*(const float4*)&XB[base+(((cq  +rot)&7)<<2)];
      float4 v1=*(const float4*)&XB[base+(((cq+1+rot)&7)<<2)];
      float4 v2=*(const float4*)&XB[base+(((cq+2+rot)&7)<<2)];
      float4 v3=*(const float4*)&XB[base+(((cq+3+rot)&7)<<2)];
      ac0.x=fmaf(ws,v0.x,ac0.x); ac0.y=fmaf(ws,v0.y,ac0.y); ac0.z=fmaf(ws,v0.z,ac0.z); ac0.w=fmaf(ws,v0.w,ac0.w);
      ac1.x=fmaf(ws,v1.x,ac1.x); ac1.y=fmaf(ws,v1.y,ac1.y); ac1.z=fmaf(ws,v1.z,ac1.z); ac1.w=fmaf(ws,v1.w,ac1.w);
      ac2.x=fmaf(ws,v2.x,ac2.x); ac2.y=fmaf(ws,v2.y,ac2.y); ac2.z=fmaf(ws,v2.z,ac2.z); ac2.w=fmaf(ws,v2.w,ac2.w);
      ac3.x=fmaf(ws,v3.x,ac3.x); ac3.y=fmaf(ws,v3.y,ac3.y); ac3.z=fmaf(ws,v3.z,ac3.z); ac3.w=fmaf(ws,v3.w,ac3.w);
    }
    float* dp=&AGG[gnode*SA + (hf<<4)];
    ((float4*)dp)[0]=ac0; ((float4*)dp)[1]=ac1; ((float4*)dp)[2]=ac2;
    if (!hf) ((float4*)dp)[3]=ac3;
    else     *(float2*)(dp+12) = make_float2(ac3.x,ac3.y);
  }
  __syncthreads();                       // x dead; agg1 ready

  // ---- load W1^T (stride 36) into XB ----
  for (int l=tid;l<FIN*H1;l+=NT){ int i=l/H1, o=l-i*H1; XB[o*SA+i]=W1[l]; }
  __syncthreads();

  // ================= mm1: h = relu(agg1 @ W1 + b1) -> regs ===================
  float h[15];
  {
    const float* arow=&AGG[nA*SA];
    float4 a0=((const float4*)arow)[0],a1=((const float4*)arow)[1],a2=((const float4*)arow)[2],
           a3=((const float4*)arow)[3],a4=((const float4*)arow)[4],a5=((const float4*)arow)[5],
           a6=((const float4*)arow)[6];
    float2 a7=*(const float2*)(arow+28);
    const int ob=hf*15;
    #pragma unroll
    for (int jo=0;jo<15;jo++){
      const float* wr=&XB[(ob+jo)*SA];
      float4 w0=((const float4*)wr)[0],w1=((const float4*)wr)[1],w2=((const float4*)wr)[2],
             w3=((const float4*)wr)[3],w4=((const float4*)wr)[4],w5=((const float4*)wr)[5],
             w6=((const float4*)wr)[6];
      float2 w7=*(const float2*)(wr+28);
      float s = a0.x*w0.x+a0.y*w0.y+a0.z*w0.z+a0.w*w0.w
              + a1.x*w1.x+a1.y*w1.y+a1.z*w1.z+a1.w*w1.w
              + a2.x*w2.x+a2.y*w2.y+a2.z*w2.z+a2.w*w2.w
              + a3.x*w3.x+a3.y*w3.y+a3.z*w3.z+a3.w*w3.w
              + a4.x*w4.x+a4.y*w4.y+a4.z*w4.z+a4.w*w4.w
              + a5.x*w5.x+a5.y*w5.y+a5.z*w5.z+a5.w*w5.w
              + a6.x*w6.x+a6.y*w6.y+a6.z*w6.z+a6.w*w6.w
              + a7.x*w7.x+a7.y*w7.y;
      h[jo]=fmaxf(s+b1[ob+jo],0.f);
    }
  }

  // ================= pool1: score, pair-split rank, gate+compact =============
  {
    float nr=0.f;
    #pragma unroll
    for (int i=0;i<H1;i++){ float pv=p1[i]; nr+=pv*pv; }
    float oth[15];
    #pragma unroll
    for (int j=0;j<15;j++) oth[j]=__shfl_xor(h[j],1,64);
    float d=0.f;
    #pragma unroll
    for (int j=0;j<15;j++) d += h[j]*p1[j];
    #pragma unroll
    for (int j=0;j<15;j++) d += oth[j]*p1[15+j];
    float scv = tanhf(d/sqrtf(nr));
    __syncthreads();                 // dinv1 / W1t reads complete
    if (!hf) dsc[nA]=scv;
  }
  __syncthreads();
  {
    float si=dsc[nA];
    int m0=hf<<6, m1=m0+64, r=0;
    for (int m=m0;m<m1;m++){ float sm=dsc[m]; r += (sm>si)||(sm==si&&m<nA); }
    r += __shfl_xor(r,1,64);
    if (!hf) rmap[nA]=(r<K1)?(signed char)r:(signed char)-1;
  }
  __syncthreads();
  {  // gated compact -> swizzled XB rows by rank
    int r=rmap[nA];
    if (r>=0){
      float gv=dsc[nA];
      const int ob=hf*15;
      #pragma unroll
      for (int j=0;j<15;j++){
        int i=ob+j;
        XB[(r<<5) + ((((i>>2)+r)&7)<<2) + (i&3)] = h[j]*gv;
      }
    }
  }
  #pragma unroll
  for (int j=0;j<EPT;j++){
    int ns=rmap[es[j]], nd=rmap[ed[j]];
    if ((ns|nd)<0){ es[j]=-1; ed[j]=0; } else { es[j]=ns; ed[j]=nd; }
  }
  if (tid<K1) cur[tid]=0;
  __syncthreads();

  // ================= CSR build 2 =================
  #pragma unroll
  for (int j=0;j<EPT;j++) if (es[j]>=0) atomicAdd(&cur[ed[j]],1);
  __syncthreads();
  {
    int dn = (nA<K1)? cur[nA] : 0;
    int m0 = hf? 52:0, m1 = hf? K1:52;
    int rk = 0;
    for (int m=m0;m<m1;m++){ int d=cur[m]; rk += (d>dn)||(d==dn && m<nA); }
    rk += __shfl_xor(rk,1,64);
    int mydeg = (tid<K1)? cur[tid] : 0;
    int v = mydeg;
    #pragma unroll
    for (int off=1; off<64; off<<=1){ int t=__shfl_up(v,off,64); if (lane>=off) v+=t; }
    if (tid==63) sh_wtot=v;
    __syncthreads();
    int start = v - mydeg + ((tid>=64)? sh_wtot : 0);
    if (tid<K1){ cur[tid]=start; cstart[tid]=(short)start; dsc[tid]=1.0f/sqrtf((float)mydeg+1.0f); }
    if (!hf && nA<K1) dperm[rk]=(unsigned char)nA;
  }
  __syncthreads();
  #pragma unroll
  for (int j=0;j<EPT;j++) if (es[j]>=0){ int p=atomicAdd(&cur[ed[j]],1); eord[p]=(unsigned char)es[j]; }
  __syncthreads();

  // ================= gather2: agg2 = A2~ * h1g (balanced, pipelined) =========
  if (tid<2*K1){
    const int gnode = dperm[nA];
    float4 ac0={0,0,0,0},ac1={0,0,0,0},ac2={0,0,0,0},ac3={0,0,0,0};
    const int cq = hf<<2;
    int e0=cstart[gnode], e1=cur[gnode];
    float di=dsc[gnode];
    int s=0; float w=0.f;
    if (e0<e1){ s=eord[e0]; w=di*dsc[s]; }
    for (int k=e0;k<e1;k++){
      int s2=0; float w2=0.f;
      if (k+1<e1){ s2=eord[k+1]; w2=di*dsc[s2]; }
      int base=s<<5, rot=s&7;
      float4 v0=*(const float4*)&XB[base+(((cq  +rot)&7)<<2)];
      float4 v1=*(const float4*)&XB[base+(((cq+1+rot)&7)<<2)];
      float4 v2=*(const float4*)&XB[base+(((cq+2+rot)&7)<<2)];
      float4 v3=*(const float4*)&XB[base+(((cq+3+rot)&7)<<2)];
      ac0.x=fmaf(w,v0.x,ac0.x); ac0.y=fmaf(w,v0.y,ac0.y); ac0.z=fmaf(w,v0.z,ac0.z); ac0.w=fmaf(w,v0.w,ac0.w);
      ac1.x=fmaf(w,v1.x,ac1.x); ac1.y=fmaf(w,v1.y,ac1.y); ac1.z=fmaf(w,v1.z,ac1.z); ac1.w=fmaf(w,v1.w,ac1.w);
      ac2.x=fmaf(w,v2.x,ac2.x); ac2.y=fmaf(w,v2.y,ac2.y); ac2.z=fmaf(w,v2.z,ac2.z); ac2.w=fmaf(w,v2.w,ac2.w);
      ac3.x=fmaf(w,v3.x,ac3.x); ac3.y=fmaf(w,v3.y,ac3.y); ac3.z=fmaf(w,v3.z,ac3.z); ac3.w=fmaf(w,v3.w,ac3.w);
      s=s2; w=w2;
    }
    {
      float ws=1.0f/((float)(e1-e0)+1.0f);
      int base=gnode<<5, rot=gnode&7;
      float4 v0=*(const float4*)&XB[base+(((cq  +rot)&7)<<2)];
      float4 v1=*(const float4*)&XB[base+(((cq+1+rot)&7)<<2)];
      float4 v2=*(const float4*)&XB[base+(((cq+2+rot)&7)<<2)];
      float4 v3=*(const float4*)&XB[base+(((cq+3+rot)&7)<<2)];
      ac0.x=fmaf(ws,v0.x,ac0.x); ac0.y=fmaf(ws,v0.y,ac0.y); ac0.z=fmaf(ws,v0.z,ac0.z); ac0.w=fmaf(ws,v0.w,ac0.w);
      ac1.x=fmaf(ws,v1.x,ac1.x); ac1.y=fmaf(ws,v1.y,ac1.y); ac1.z=fmaf(ws,v1.z,ac1.z); ac1.w=fmaf(ws,v1.w,ac1.w);
      ac2.x=fmaf(ws,v2.x,ac2.x); ac2.y=fmaf(ws,v2.y,ac2.y); ac2.z=fmaf(ws,v2.z,ac2.z); ac2.w=fmaf(ws,v2.w,ac2.w);
      ac3.x=fmaf(ws,v3.x,ac3.x); ac3.y=fmaf(ws,v3.y,ac3.y); ac3.z=fmaf(ws,v3.z,ac3.z); ac3.w=fmaf(ws,v3.w,ac3.w);
    }
    float* dp=&AGG[gnode*SA + (hf<<4)];
    ((float4*)dp)[0]=ac0; ((float4*)dp)[1]=ac1; ((float4*)dp)[2]=ac2;
    if (!hf) ((float4*)dp)[3]=ac3;
    else     *(float2*)(dp+12) = make_float2(ac3.x,ac3.y);
  }
  __syncthreads();                       // h1g dead; agg2 ready

  // ---- load W2^T (stride 36) into XB ----
  for (int l=tid;l<H1*H2;l+=NT){ int i=l/H2, o=l-i*H2; XB[o*SA+i]=W2[l]; }
  __syncthreads();

  // ================= mm2: h2 = relu(agg2 @ W2 + b2) -> regs ==================
  float oacc[25];
  if (tid<2*K1){
    const float* arow=&AGG[nA*SA];
    float4 a0=((const float4*)arow)[0],a1=((const float4*)arow)[1],a2=((const float4*)arow)[2],
           a3=((const float4*)arow)[3],a4=((const float4*)arow)[4],a5=((const float4*)arow)[5],
           a6=((const float4*)arow)[6];
    float2 a7=*(const float2*)(arow+28);
    const int ob=hf*25;
    #pragma unroll
    for (int jo=0;jo<25;jo++){
      const float* wr=&XB[(ob+jo)*SA];
      float4 w0=((const float4*)wr)[0],w1=((const float4*)wr)[1],w2=((const float4*)wr)[2],
             w3=((const float4*)wr)[3],w4=((const float4*)wr)[4],w5=((const float4*)wr)[5],
             w6=((const float4*)wr)[6];
      float2 w7=*(const float2*)(wr+28);
      float s = a0.x*w0.x+a0.y*w0.y+a0.z*w0.z+a0.w*w0.w
              + a1.x*w1.x+a1.y*w1.y+a1.z*w1.z+a1.w*w1.w
              + a2.x*w2.x+a2.y*w2.y+a2.z*w2.z+a2.w*w2.w
              + a3.x*w3.x+a3.y*w3.y+a3.z*w3.z+a3.w*w3.w
              + a4.x*w4.x+a4.y*w4.y+a4.z*w4.z+a4.w*w4.w
              + a5.x*w5.x+a5.y*w5.y+a5.z*w5.z+a5.w*w5.w
              + a6.x*w6.x+a6.y*w6.y+a6.z*w6.z+a6.w*w6.w
              + a7.x*w7.x+a7.y*w7.y;
      oacc[jo]=fmaxf(s+b2[ob+jo],0.f);
    }
  }

  // ================= pool2 score + pair-split rank =================
  {
    float nr=0.f;
    #pragma unroll
    for (int i=0;i<H2;i++){ float pv=p2[i]; nr+=pv*pv; }
    float oth[25];
    #pragma unroll
    for (int j=0;j<25;j++) oth[j]=__shfl_xor(oacc[j],1,64);
    float d=0.f;
    #pragma unroll
    for (int j=0;j<25;j++) d += oacc[j]*p2[j];
    #pragma unroll
    for (int j=0;j<25;j++) d += oth[j]*p2[25+j];
    float scv = tanhf(d/sqrtf(nr));
    __syncthreads();                 // dinv2 reads done
    if (tid<2*K1 && !hf) dsc[nA]=scv;
  }
  __syncthreads();
  {
    float si=(nA<K1)? dsc[nA]:0.f;
    int m0= hf? 52:0, m1= hf? K1:52, r=0;
    for (int m=m0;m<m1;m++){ float sm=dsc[m]; r += (sm>si)||(sm==si&&m<nA); }
    r += __shfl_xor(r,1,64);
    if (!hf && nA<K1) rmap[nA]=(r<K2)?(signed char)1:(signed char)-1;
  }
  __syncthreads();

  // ================= register-space gated global max/mean ====================
  {
    bool kept = (tid<2*K1) && (rmap[nA]>0);
    float gv  = kept ? dsc[nA] : 0.f;
    float mx[25], sm[25];
    #pragma unroll
    for (int j=0;j<25;j++){
      float v=oacc[j]*gv;
      sm[j]= kept ? v : 0.f;
      mx[j]= kept ? v : -3.4e38f;
    }
    #pragma unroll
    for (int off=2; off<64; off<<=1){
      #pragma unroll
      for (int j=0;j<25;j++){
        mx[j]=fmaxf(mx[j],__shfl_xor(mx[j],off,64));
        sm[j]+=__shfl_xor(sm[j],off,64);
      }
    }
    int wv=tid>>6;
    if (lane<2){
      #pragma unroll
      for (int j=0;j<25;j++){
        AGG[PMAXo + wv*50 + lane*25 + j]=mx[j];
        AGG[PSUMo + wv*50 + lane*25 + j]=sm[j];
      }
    }
  }
  __syncthreads();
  if (tid<H2){
    float m=-3.4e38f, s=0.f;
    #pragma unroll
    for (int w=0;w<4;w++){ m=fmaxf(m,AGG[PMAXo+w*50+tid]); s+=AGG[PSUMo+w*50+tid]; }
    AGG[POOLo+tid]=m;
    AGG[POOLo+H2+tid]=s*(1.0f/(float)K2);
  }
  __syncthreads();

  // ================= fc1 + fc2 =================
  if (tid<FCW){
    float acc=fc1b[tid];
    #pragma unroll 4
    for (int i=0;i<2*H2;i++) acc += AGG[POOLo+i]*fc1W[i*FCW+tid];
    AGG[ZFCo+tid]=fmaxf(acc,0.f);
  }
  __syncthreads();
  if (tid<64){
    float a=0.f;
    for (int j=tid;j<FCW;j+=64) a += AGG[ZFCo+j]*fc2W[j];
    #pragma unroll
    for (int off=32;off;off>>=1) a += __shfl_down(a,off,64);
    if (tid==0){
      float acc=fc2b[0]+a;
      out[g]=1.0f/(1.0f+expf(-acc));
    }
  }
}

extern "C" void kernel_launch(void* const* d_in, const int* in_sizes, int n_in,
                              void* d_out, int out_size, void* d_ws, size_t ws_size,
                              hipStream_t stream) {
  const float* x    = (const float*)d_in[0];
  const int*   ei   = (const int*)d_in[1];
  // d_in[2] = batch (unused; graphs are equal-size, contiguous)
  const float* W1   = (const float*)d_in[3];
  const float* b1   = (const float*)d_in[4];
  const float* p1   = (const float*)d_in[5];
  const float* W2   = (const float*)d_in[6];
  const float* b2   = (const float*)d_in[7];
  const float* p2   = (const float*)d_in[8];
  const float* fc1W = (const float*)d_in[9];
  const float* fc1b = (const float*)d_in[10];
  const float* fc2W = (const float*)d_in[11];
  const float* fc2b = (const float*)d_in[12];
  float* outp = (float*)d_out;

  gnn_fused<<<BGR, NT, 0, stream>>>(x, ei, W1, b1, p1, W2, b2, p2,
                                    fc1W, fc1b, fc2W, fc2b, outp);
}

// Round 6
// 70.047 us; speedup vs baseline: 1.0639x; 1.0639x over previous
//
#include <hip/hip_runtime.h>
#include <math.h>

// Problem constants (match reference)
constexpr int BGR = 1024;   // graphs
constexpr int NN  = 128;    // nodes per graph
constexpr int EG  = 2048;   // edges per graph
constexpr int FIN = 30;
constexpr int H1  = 30;
constexpr int H2  = 50;
constexpr int K1  = 103;    // ceil(0.8*128)
constexpr int K2  = 83;     // ceil(0.8*103)
constexpr int FCW = 100;
constexpr int NT  = 256;
constexpr int EPT = EG/NT;  // 8 edges/thread in registers

// XB: node rows of 32 floats, chunk-rotated swizzle:
//   feature i of row s -> dword s*32 + (((i>>2)+s)&7)*4 + (i&3)
// AGG: aggregated rows, stride 36 floats.
constexpr int SA   = 36;
constexpr int XBSZ = NN*32;        // 16384 B
constexpr int AGSZ = NN*SA;        // 18432 B
constexpr int EGP  = EG + NN*4;    // padded CSR capacity (deg rounded up to x4)
// AGG tail scratch (rows >=104 unused: dword 3744..4607)
constexpr int PMAXo = 3744;
constexpr int PSUMo = 3944;
constexpr int POOLo = 4144;
constexpr int ZFCo  = 4244;

__device__ __forceinline__ void row_fma(int s, float w, const float* XB, int cq,
                                        float4& ac0, float4& ac1, float4& ac2, float4& ac3)
{
  int base=s<<5, rot=s&7;
  float4 v0=*(const float4*)&XB[base+(((cq  +rot)&7)<<2)];
  float4 v1=*(const float4*)&XB[base+(((cq+1+rot)&7)<<2)];
  float4 v2=*(const float4*)&XB[base+(((cq+2+rot)&7)<<2)];
  float4 v3=*(const float4*)&XB[base+(((cq+3+rot)&7)<<2)];
  ac0.x=fmaf(w,v0.x,ac0.x); ac0.y=fmaf(w,v0.y,ac0.y); ac0.z=fmaf(w,v0.z,ac0.z); ac0.w=fmaf(w,v0.w,ac0.w);
  ac1.x=fmaf(w,v1.x,ac1.x); ac1.y=fmaf(w,v1.y,ac1.y); ac1.z=fmaf(w,v1.z,ac1.z); ac1.w=fmaf(w,v1.w,ac1.w);
  ac2.x=fmaf(w,v2.x,ac2.x); ac2.y=fmaf(w,v2.y,ac2.y); ac2.z=fmaf(w,v2.z,ac2.z); ac2.w=fmaf(w,v2.w,ac2.w);
  ac3.x=fmaf(w,v3.x,ac3.x); ac3.y=fmaf(w,v3.y,ac3.y); ac3.z=fmaf(w,v3.z,ac3.z); ac3.w=fmaf(w,v3.w,ac3.w);
}

__global__ __launch_bounds__(NT, 4) void gnn_fused(
    const float* __restrict__ x, const int* __restrict__ ei,
    const float* __restrict__ W1, const float* __restrict__ b1, const float* __restrict__ p1,
    const float* __restrict__ W2, const float* __restrict__ b2, const float* __restrict__ p2,
    const float* __restrict__ fc1W, const float* __restrict__ fc1b,
    const float* __restrict__ fc2W, const float* __restrict__ fc2b,
    float* __restrict__ out)
{
  const int g = blockIdx.x, tid = threadIdx.x;

  __shared__ float XB[XBSZ];          // x -> W1t -> h1-gated -> W2t
  __shared__ float AGG[AGSZ];         // agg1 -> agg2 (+ tail scratch)
  __shared__ unsigned char eord[EGP]; // padded CSR source ids (0xFF = hole)
  __shared__ int   cur[NN];
  __shared__ short cstart[NN];        // padded starts
  __shared__ float dsc[NN];           // dinv <-> score (barrier-guarded)
  __shared__ signed char rmap[NN];
  __shared__ int sh_wtot;

  // ---- edge list in registers for the whole kernel ----
  int es[EPT], ed[EPT];
  {
    const int* srcg = ei + (size_t)g*EG;
    const int* dstg = ei + (size_t)BGR*EG + (size_t)g*EG;
    #pragma unroll
    for (int j=0;j<EPT;j++){ int e=tid+j*NT; es[j]=srcg[e]&(NN-1); ed[j]=dstg[e]&(NN-1); }
  }
  // ---- stage x into swizzled XB (float2: 30 feats = 15 pairs/node) ----
  for (int l2=tid; l2<NN*15; l2+=NT){
    int n=l2/15, i=(l2-n*15)*2;
    float2 v=*(const float2*)&x[(size_t)g*NN*FIN + n*FIN + i];
    *(float2*)&XB[(n<<5) + ((((i>>2)+n)&7)<<2) + (i&3)] = v;
  }
  if (tid<NN) cur[tid]=0;
  __syncthreads();

  const int nA = tid>>1, hf = tid&1;
  const int lane = tid&63;

  // ================= CSR build 1 (count -> scan(pad4) -> fill -> scatter) ====
  #pragma unroll
  for (int j=0;j<EPT;j++) atomicAdd(&cur[ed[j]],1);
  __syncthreads();
  {
    int mydeg = (tid<NN)? cur[tid] : 0;
    int mydeg4=(mydeg+3)&~3;
    int v = mydeg4;
    #pragma unroll
    for (int off=1; off<64; off<<=1){ int t=__shfl_up(v,off,64); if (lane>=off) v+=t; }
    if (tid==63) sh_wtot=v;
    for (int l=tid;l<EGP/4;l+=NT) ((int*)eord)[l]=-1;     // holes = 0xFF
    __syncthreads();
    int start = v - mydeg4 + ((tid>=64)? sh_wtot : 0);
    if (tid<NN){ cur[tid]=start; cstart[tid]=(short)start; dsc[tid]=1.0f/sqrtf((float)mydeg+1.0f); }
  }
  __syncthreads();
  #pragma unroll
  for (int j=0;j<EPT;j++){ int p=atomicAdd(&cur[ed[j]],1); eord[p]=(unsigned char)es[j]; }
  __syncthreads();

  // ================= gather1: agg1 = A~ * x (uchar4-batched) ================
  {
    float4 ac0={0,0,0,0},ac1={0,0,0,0},ac2={0,0,0,0},ac3={0,0,0,0};
    const int cq = hf<<2;
    int e0=cstart[nA], deg=cur[nA]-e0;
    float di=dsc[nA];
    int kend=e0+((deg+3)&~3);
    for (int k=e0;k<kend;k+=4){
      uchar4 ss=*(const uchar4*)&eord[k];
      float w0=(ss.x<128)? di*dsc[ss.x&127] : 0.f;
      float w1=(ss.y<128)? di*dsc[ss.y&127] : 0.f;
      float w2=(ss.z<128)? di*dsc[ss.z&127] : 0.f;
      float w3=(ss.w<128)? di*dsc[ss.w&127] : 0.f;
      row_fma(ss.x&127,w0,XB,cq,ac0,ac1,ac2,ac3);
      row_fma(ss.y&127,w1,XB,cq,ac0,ac1,ac2,ac3);
      row_fma(ss.z&127,w2,XB,cq,ac0,ac1,ac2,ac3);
      row_fma(ss.w&127,w3,XB,cq,ac0,ac1,ac2,ac3);
    }
    row_fma(nA, 1.0f/((float)deg+1.0f), XB, cq, ac0,ac1,ac2,ac3);   // self loop
    float* dp=&AGG[nA*SA + (hf<<4)];
    ((float4*)dp)[0]=ac0; ((float4*)dp)[1]=ac1; ((float4*)dp)[2]=ac2;
    if (!hf) ((float4*)dp)[3]=ac3;
    else     *(float2*)(dp+12) = make_float2(ac3.x,ac3.y);
  }
  __syncthreads();                       // x dead; agg1 ready

  // ---- load W1^T (stride 36) into XB ----
  for (int l=tid;l<FIN*H1;l+=NT){ int i=l/H1, o=l-i*H1; XB[o*SA+i]=W1[l]; }
  __syncthreads();

  // ================= mm1: h = relu(agg1 @ W1 + b1) -> regs ===================
  float h[15];
  {
    const float* arow=&AGG[nA*SA];
    float4 a0=((const float4*)arow)[0],a1=((const float4*)arow)[1],a2=((const float4*)arow)[2],
           a3=((const float4*)arow)[3],a4=((const float4*)arow)[4],a5=((const float4*)arow)[5],
           a6=((const float4*)arow)[6];
    float2 a7=*(const float2*)(arow+28);
    const int ob=hf*15;
    #pragma unroll
    for (int jo=0;jo<15;jo++){
      const float* wr=&XB[(ob+jo)*SA];
      float4 w0=((const float4*)wr)[0],w1=((const float4*)wr)[1],w2=((const float4*)wr)[2],
             w3=((const float4*)wr)[3],w4=((const float4*)wr)[4],w5=((const float4*)wr)[5],
             w6=((const float4*)wr)[6];
      float2 w7=*(const float2*)(wr+28);
      float s = a0.x*w0.x+a0.y*w0.y+a0.z*w0.z+a0.w*w0.w
              + a1.x*w1.x+a1.y*w1.y+a1.z*w1.z+a1.w*w1.w
              + a2.x*w2.x+a2.y*w2.y+a2.z*w2.z+a2.w*w2.w
              + a3.x*w3.x+a3.y*w3.y+a3.z*w3.z+a3.w*w3.w
              + a4.x*w4.x+a4.y*w4.y+a4.z*w4.z+a4.w*w4.w
              + a5.x*w5.x+a5.y*w5.y+a5.z*w5.z+a5.w*w5.w
              + a6.x*w6.x+a6.y*w6.y+a6.z*w6.z+a6.w*w6.w
              + a7.x*w7.x+a7.y*w7.y;
      h[jo]=fmaxf(s+b1[ob+jo],0.f);
    }
  }

  // ================= pool1: score, pair-split rank, gate+compact =============
  {
    float nr=0.f;
    #pragma unroll
    for (int i=0;i<H1;i++){ float pv=p1[i]; nr+=pv*pv; }
    float oth[15];
    #pragma unroll
    for (int j=0;j<15;j++) oth[j]=__shfl_xor(h[j],1,64);
    float d=0.f;
    #pragma unroll
    for (int j=0;j<15;j++) d += h[j]*p1[j];
    #pragma unroll
    for (int j=0;j<15;j++) d += oth[j]*p1[15+j];
    float scv = tanhf(d/sqrtf(nr));
    __syncthreads();                 // dinv1 / W1t reads complete
    if (!hf) dsc[nA]=scv;
  }
  __syncthreads();
  {
    float si=dsc[nA];
    int m0=hf<<6, m1=m0+64, r=0;
    for (int m=m0;m<m1;m++){ float sm=dsc[m]; r += (sm>si)||(sm==si&&m<nA); }
    r += __shfl_xor(r,1,64);
    if (!hf) rmap[nA]=(r<K1)?(signed char)r:(signed char)-1;
  }
  __syncthreads();
  {  // gated compact -> swizzled XB rows by rank
    int r=rmap[nA];
    if (r>=0){
      float gv=dsc[nA];
      const int ob=hf*15;
      #pragma unroll
      for (int j=0;j<15;j++){
        int i=ob+j;
        XB[(r<<5) + ((((i>>2)+r)&7)<<2) + (i&3)] = h[j]*gv;
      }
    }
  }
  #pragma unroll
  for (int j=0;j<EPT;j++){
    int ns=rmap[es[j]], nd=rmap[ed[j]];
    if ((ns|nd)<0){ es[j]=-1; ed[j]=0; } else { es[j]=ns; ed[j]=nd; }
  }
  if (tid<K1) cur[tid]=0;
  __syncthreads();

  // ================= CSR build 2 =================
  #pragma unroll
  for (int j=0;j<EPT;j++) if (es[j]>=0) atomicAdd(&cur[ed[j]],1);
  __syncthreads();
  {
    int mydeg = (tid<K1)? cur[tid] : 0;
    int mydeg4=(mydeg+3)&~3;
    int v = mydeg4;
    #pragma unroll
    for (int off=1; off<64; off<<=1){ int t=__shfl_up(v,off,64); if (lane>=off) v+=t; }
    if (tid==63) sh_wtot=v;
    for (int l=tid;l<EGP/4;l+=NT) ((int*)eord)[l]=-1;
    __syncthreads();
    int start = v - mydeg4 + ((tid>=64)? sh_wtot : 0);
    if (tid<K1){ cur[tid]=start; cstart[tid]=(short)start; dsc[tid]=1.0f/sqrtf((float)mydeg+1.0f); }
  }
  __syncthreads();
  #pragma unroll
  for (int j=0;j<EPT;j++) if (es[j]>=0){ int p=atomicAdd(&cur[ed[j]],1); eord[p]=(unsigned char)es[j]; }
  __syncthreads();

  // ================= gather2: agg2 = A2~ * h1g (uchar4-batched) ==============
  if (tid<2*K1){
    float4 ac0={0,0,0,0},ac1={0,0,0,0},ac2={0,0,0,0},ac3={0,0,0,0};
    const int cq = hf<<2;
    int e0=cstart[nA], deg=cur[nA]-e0;
    float di=dsc[nA];
    int kend=e0+((deg+3)&~3);
    for (int k=e0;k<kend;k+=4){
      uchar4 ss=*(const uchar4*)&eord[k];
      float w0=(ss.x<128)? di*dsc[ss.x&127] : 0.f;
      float w1=(ss.y<128)? di*dsc[ss.y&127] : 0.f;
      float w2=(ss.z<128)? di*dsc[ss.z&127] : 0.f;
      float w3=(ss.w<128)? di*dsc[ss.w&127] : 0.f;
      row_fma(ss.x&127,w0,XB,cq,ac0,ac1,ac2,ac3);
      row_fma(ss.y&127,w1,XB,cq,ac0,ac1,ac2,ac3);
      row_fma(ss.z&127,w2,XB,cq,ac0,ac1,ac2,ac3);
      row_fma(ss.w&127,w3,XB,cq,ac0,ac1,ac2,ac3);
    }
    row_fma(nA, 1.0f/((float)deg+1.0f), XB, cq, ac0,ac1,ac2,ac3);
    float* dp=&AGG[nA*SA + (hf<<4)];
    ((float4*)dp)[0]=ac0; ((float4*)dp)[1]=ac1; ((float4*)dp)[2]=ac2;
    if (!hf) ((float4*)dp)[3]=ac3;
    else     *(float2*)(dp+12) = make_float2(ac3.x,ac3.y);
  }
  __syncthreads();                       // h1g dead; agg2 ready

  // ---- load W2^T (stride 36) into XB ----
  for (int l=tid;l<H1*H2;l+=NT){ int i=l/H2, o=l-i*H2; XB[o*SA+i]=W2[l]; }
  __syncthreads();

  // ================= mm2: h2 = relu(agg2 @ W2 + b2) -> regs ==================
  float oacc[25];
  if (tid<2*K1){
    const float* arow=&AGG[nA*SA];
    float4 a0=((const float4*)arow)[0],a1=((const float4*)arow)[1],a2=((const float4*)arow)[2],
           a3=((const float4*)arow)[3],a4=((const float4*)arow)[4],a5=((const float4*)arow)[5],
           a6=((const float4*)arow)[6];
    float2 a7=*(const float2*)(arow+28);
    const int ob=hf*25;
    #pragma unroll
    for (int jo=0;jo<25;jo++){
      const float* wr=&XB[(ob+jo)*SA];
      float4 w0=((const float4*)wr)[0],w1=((const float4*)wr)[1],w2=((const float4*)wr)[2],
             w3=((const float4*)wr)[3],w4=((const float4*)wr)[4],w5=((const float4*)wr)[5],
             w6=((const float4*)wr)[6];
      float2 w7=*(const float2*)(wr+28);
      float s = a0.x*w0.x+a0.y*w0.y+a0.z*w0.z+a0.w*w0.w
              + a1.x*w1.x+a1.y*w1.y+a1.z*w1.z+a1.w*w1.w
              + a2.x*w2.x+a2.y*w2.y+a2.z*w2.z+a2.w*w2.w
              + a3.x*w3.x+a3.y*w3.y+a3.z*w3.z+a3.w*w3.w
              + a4.x*w4.x+a4.y*w4.y+a4.z*w4.z+a4.w*w4.w
              + a5.x*w5.x+a5.y*w5.y+a5.z*w5.z+a5.w*w5.w
              + a6.x*w6.x+a6.y*w6.y+a6.z*w6.z+a6.w*w6.w
              + a7.x*w7.x+a7.y*w7.y;
      oacc[jo]=fmaxf(s+b2[ob+jo],0.f);
    }
  }

  // ================= pool2 score + pair-split rank =================
  {
    float nr=0.f;
    #pragma unroll
    for (int i=0;i<H2;i++){ float pv=p2[i]; nr+=pv*pv; }
    float oth[25];
    #pragma unroll
    for (int j=0;j<25;j++) oth[j]=__shfl_xor(oacc[j],1,64);
    float d=0.f;
    #pragma unroll
    for (int j=0;j<25;j++) d += oacc[j]*p2[j];
    #pragma unroll
    for (int j=0;j<25;j++) d += oth[j]*p2[25+j];
    float scv = tanhf(d/sqrtf(nr));
    __syncthreads();                 // dinv2 reads done
    if (tid<2*K1 && !hf) dsc[nA]=scv;
  }
  __syncthreads();
  {
    float si=(nA<K1)? dsc[nA]:0.f;
    int m0= hf? 52:0, m1= hf? K1:52, r=0;
    for (int m=m0;m<m1;m++){ float sm=dsc[m]; r += (sm>si)||(sm==si&&m<nA); }
    r += __shfl_xor(r,1,64);
    if (!hf && nA<K1) rmap[nA]=(r<K2)?(signed char)1:(signed char)-1;
  }
  __syncthreads();

  // ================= register-space gated global max/mean ====================
  {
    bool kept = (tid<2*K1) && (rmap[nA]>0);
    float gv  = kept ? dsc[nA] : 0.f;
    float mx[25], sm[25];
    #pragma unroll
    for (int j=0;j<25;j++){
      float v=oacc[j]*gv;
      sm[j]= kept ? v : 0.f;
      mx[j]= kept ? v : -3.4e38f;
    }
    #pragma unroll
    for (int off=2; off<64; off<<=1){
      #pragma unroll
      for (int j=0;j<25;j++){
        mx[j]=fmaxf(mx[j],__shfl_xor(mx[j],off,64));
        sm[j]+=__shfl_xor(sm[j],off,64);
      }
    }
    int wv=tid>>6;
    if (lane<2){
      #pragma unroll
      for (int j=0;j<25;j++){
        AGG[PMAXo + wv*50 + lane*25 + j]=mx[j];
        AGG[PSUMo + wv*50 + lane*25 + j]=sm[j];
      }
    }
  }
  __syncthreads();
  if (tid<H2){
    float m=-3.4e38f, s=0.f;
    #pragma unroll
    for (int w=0;w<4;w++){ m=fmaxf(m,AGG[PMAXo+w*50+tid]); s+=AGG[PSUMo+w*50+tid]; }
    AGG[POOLo+tid]=m;
    AGG[POOLo+H2+tid]=s*(1.0f/(float)K2);
  }
  __syncthreads();

  // ================= fc1 + fc2 =================
  if (tid<FCW){
    float acc=fc1b[tid];
    #pragma unroll 4
    for (int i=0;i<2*H2;i++) acc += AGG[POOLo+i]*fc1W[i*FCW+tid];
    AGG[ZFCo+tid]=fmaxf(acc,0.f);
  }
  __syncthreads();
  if (tid<64){
    float a=0.f;
    for (int j=tid;j<FCW;j+=64) a += AGG[ZFCo+j]*fc2W[j];
    #pragma unroll
    for (int off=32;off;off>>=1) a += __shfl_down(a,off,64);
    if (tid==0){
      float acc=fc2b[0]+a;
      out[g]=1.0f/(1.0f+expf(-acc));
    }
  }
}

extern "C" void kernel_launch(void* const* d_in, const int* in_sizes, int n_in,
                              void* d_out, int out_size, void* d_ws, size_t ws_size,
                              hipStream_t stream) {
  const float* x    = (const float*)d_in[0];
  const int*   ei   = (const int*)d_in[1];
  // d_in[2] = batch (unused; graphs are equal-size, contiguous)
  const float* W1   = (const float*)d_in[3];
  const float* b1   = (const float*)d_in[4];
  const float* p1   = (const float*)d_in[5];
  const float* W2   = (const float*)d_in[6];
  const float* b2   = (const float*)d_in[7];
  const float* p2   = (const float*)d_in[8];
  const float* fc1W = (const float*)d_in[9];
  const float* fc1b = (const float*)d_in[10];
  const float* fc2W = (const float*)d_in[11];
  const float* fc2b = (const float*)d_in[12];
  float* outp = (float*)d_out;

  gnn_fused<<<BGR, NT, 0, stream>>>(x, ei, W1, b1, p1, W2, b2, p2,
                                    fc1W, fc1b, fc2W, fc2b, outp);
}